// Round 1
// baseline (208.168 us; speedup 1.0000x reference)
//
#include <hip/hip_runtime.h>
#include <hip/hip_bf16.h>
#include <math.h>

#define FLn 96
#define SEG 288      // 3*FL
#define EPS_BN 1e-5f

typedef __attribute__((ext_vector_type(8))) short short8;
typedef __attribute__((ext_vector_type(4))) float floatx4;
typedef float v2f __attribute__((ext_vector_type(2)));

__device__ __forceinline__ float lrelu(float v) { return fmaxf(v, 0.1f * v); }
__device__ __forceinline__ short f2bf(float f) {
  __hip_bfloat16 h = __float2bfloat16(f);
  return *reinterpret_cast<short*>(&h);
}

// ---------------- K1 v2: ONE wave per (sample,half) unit --------------------
// 4 units per 256-thread block, each unit entirely private to its wave:
// ZERO __syncthreads. All LDS regions are wave-private, so ordering is
// wave-program-order (compiler-inserted lgkmcnt waits). This removes the 7
// barrier drains of the 2-wave version (Occupancy was 37%, 3 waves/SIMD).
// Row/col means are reduced with shfl_xor butterflies in-register, deleting
// the RP LDS region (per-unit LDS 13.3KB -> 4.35KB).
// NOTE: no min-waves in __launch_bounds__ (R10: forcing waves/EU caused
// massive scratch spill).
// Per-unit LDS slice (float offsets): CIN 0..287, ST1 288..575, APP 576..673,
// ANP 674..771, XPP 772..869, XNP 870..967, BERT 968..1063, WKER 1064..1072.
// Overlays (producers dead by then): ABF shorts over floats 0..383
// (CIN + ST1[0..95]); BBF shorts over floats 384..767 (ST1[96..287] + APP +
// ANP[0..93]). A-build (reads APP/ANP) precedes B-build (writes BBF) in
// wave program order, so the overlay is safe without a barrier.
#define U_CIN 0
#define U_ST1 288
#define U_APP 576
#define U_ANP 674
#define U_XPP 772
#define U_XNP 870
#define U_BERT 968
#define U_WKER 1064
#define U_ABF 0
#define U_BBF 384
#define USLICE 1088   // 4352 B per unit; 17408 B per block (4 units)

__global__ __launch_bounds__(256) void k1_persample(
    const float* __restrict__ x,
    const float* __restrict__ cw1, const float* __restrict__ cb1,
    const float* __restrict__ cw2, const float* __restrict__ cb2,
    const float* __restrict__ cw3, const float* __restrict__ cb3,
    const float* __restrict__ cw4, const float* __restrict__ cb4,
    const float* __restrict__ cw5, const float* __restrict__ cb5,
    const float* __restrict__ cw6, const float* __restrict__ cb6,
    const float* __restrict__ deW, const float* __restrict__ deb,
    const float* __restrict__ rsW, const float* __restrict__ clW1,
    short* __restrict__ wB2s, short* __restrict__ wB3s,
    short* __restrict__ epre_s) {
  __shared__ float S_all[4 * USLICE];
  const int tid = threadIdx.x;
  const int w = tid >> 6;
  const int lane = tid & 63;
  const int quad = lane >> 4;
  const int l16 = lane & 15;
  const int unit = blockIdx.x * 4 + w;
  float* S = S_all + w * USLICE;
  short* Ssh = (short*)S;
  const float* xrow = x + (size_t)(unit >> 1) * 576 + (unit & 1) * 288;

  // ---- folded k0: swizzle-cast weights into MFMA-fragment order ----
  // (covered by blocks 0..647 of the 4096-block grid)
  {
    int d = blockIdx.x * 256 + tid;
    if (d < 18 * 6 * 512) {
      int j = d & 7, ln = (d >> 3) & 63, t = d >> 9;
      int kf = t % 6, nf = t / 6;
      int n = nf * 16 + (ln & 15);
      int k = kf * 32 + (ln >> 4) * 8 + j;
      wB2s[d] = f2bf(rsW[n * 192 + k]);
    }
    if (d < 18 * 18 * 512) {
      int j = d & 7, ln = (d >> 3) & 63, t = d >> 9;
      int kf = t % 18, nt = t / 18;
      int n = nt * 16 + (ln & 15);
      int k = kf * 32 + (ln >> 4) * 8 + j;
      wB3s[d] = f2bf(clW1[n * 576 + k]);
    }
  }

  const float a0w0 = cw1[0], a0w1 = cw1[1], a0w2 = cw1[2], a0b = cb1[0];
  const float a1w0 = cw2[0], a1w1 = cw2[1], a1w2 = cw2[2], a1b = cb2[0];
  const float a2w0 = cw3[0], a2w1 = cw3[1], a2w2 = cw3[2], a2b = cb3[0];
  const float b0w0 = cw4[0], b0w1 = cw4[1], b0w2 = cw4[2], b0b = cb4[0];
  const float b1w0 = cw5[0], b1w1 = cw5[1], b1w2 = cw5[2], b1b = cb5[0];
  const float b2w0 = cw6[0], b2w1 = cw6[1], b2w2 = cw6[2], b2b = cb6[0];

  // load this unit's 288 inputs (72 float4, coalesced per wave)
  for (int t4 = lane; t4 < 72; t4 += 64)
    *(float4*)&S[U_CIN + 4 * t4] = ((const float4*)xrow)[t4];
  // zero conv-boundary pads of APP/ANP/XPP/XNP
  if (lane < 8) S[U_APP + 98 * (lane >> 1) + (lane & 1) * 97] = 0.f;

  // stage-1 convs
  for (int t = lane; t < SEG; t += 64) {
    bool g1 = t >= 96, g2 = t >= 192;
    float wa = g2 ? a2w0 : (g1 ? a1w0 : a0w0);
    float wb = g2 ? a2w1 : (g1 ? a1w1 : a0w1);
    float wc = g2 ? a2w2 : (g1 ? a1w2 : a0w2);
    float bb = g2 ? a2b  : (g1 ? a1b  : a0b);
    int p = t - (g2 ? 192 : (g1 ? 96 : 0));
    float l = p > 0 ? S[U_CIN + t - 1] : 0.f;
    float m = S[U_CIN + t];
    float r = p < FLn - 1 ? S[U_CIN + t + 1] : 0.f;
    S[U_ST1 + t] = lrelu(fmaf(wa, l, fmaf(wb, m, fmaf(wc, r, bb))));
  }
  // stage-2 convs -> aPp/aNp, xpP/xnP, bert
  for (int t = lane; t < SEG; t += 64) {
    bool g1 = t >= 96, g2 = t >= 192;
    float wa = g2 ? b2w0 : (g1 ? b1w0 : b0w0);
    float wb = g2 ? b2w1 : (g1 ? b1w1 : b0w1);
    float wc = g2 ? b2w2 : (g1 ? b1w2 : b0w2);
    float bb = g2 ? b2b  : (g1 ? b1b  : b0b);
    int p = t - (g2 ? 192 : (g1 ? 96 : 0));
    float l = p > 0 ? S[U_ST1 + t - 1] : 0.f;
    float m = S[U_ST1 + t];
    float r = p < FLn - 1 ? S[U_ST1 + t + 1] : 0.f;
    float v = lrelu(fmaf(wa, l, fmaf(wb, m, fmaf(wc, r, bb))));
    if (!g1) {
      S[U_APP + 1 + p] = fmaxf(v, 0.1f * v);
      S[U_ANP + 1 + p] = fminf(v, 0.1f * v);
    } else if (!g2) {
      S[U_XPP + 1 + p] = fmaxf(v, 0.f);
      S[U_XNP + 1 + p] = fminf(v, 0.f);
    } else {
      S[U_BERT + p] = v;
    }
  }

  // per-sample 3x3 kernel (wker): quads 0..2, one output each of 3
  if (quad < 3) {
    float bv[6];
#pragma unroll
    for (int k = 0; k < 6; ++k) bv[k] = S[U_BERT + l16 + 16 * k];
#pragma unroll
    for (int oi = 0; oi < 3; ++oi) {
      int o = quad * 3 + oi;
      float p = 0.f;
#pragma unroll
      for (int k = 0; k < 6; ++k) p = fmaf(bv[k], deW[o * 96 + l16 + 16 * k], p);
      p += __shfl_xor(p, 1, 16);
      p += __shfl_xor(p, 2, 16);
      p += __shfl_xor(p, 4, 16);
      p += __shfl_xor(p, 8, 16);
      if (l16 == 0) S[U_WKER + o] = lrelu(p + deb[o]);
    }
  }

  // A-matrix build (overlays CIN/ST1lo; both dead)
  for (int m = lane; m < 96; m += 64) {
    short8 a;
    a[0] = f2bf(S[U_APP + m]);
    a[1] = f2bf(S[U_APP + m + 1]);
    a[2] = f2bf(S[U_APP + m + 2]);
    a[3] = f2bf(S[U_ANP + m]);
    a[4] = f2bf(S[U_ANP + m + 1]);
    a[5] = f2bf(S[U_ANP + m + 2]);
    a[6] = 0; a[7] = 0;
    *(short8*)&Ssh[2 * U_ABF + m * 8] = a;
  }

  // B-matrix build, 0.25-scaled (4-quad replication sums back to 1x)
  {
    float w9[9];
#pragma unroll
    for (int q = 0; q < 9; ++q) w9[q] = 0.25f * S[U_WKER + q];
    for (int t = lane; t < 96; t += 64) {
      float xp0 = S[U_XPP + t], xp1 = S[U_XPP + t + 1], xp2 = S[U_XPP + t + 2];
      float xn0 = S[U_XNP + t], xn1 = S[U_XNP + t + 1], xn2 = S[U_XNP + t + 2];
      short8 b;
#pragma unroll
      for (int d = 0; d < 3; ++d) {
        float cp = fmaf(w9[3 * d], xp0, fmaf(w9[3 * d + 1], xp1, w9[3 * d + 2] * xp2));
        float cn = fmaf(w9[3 * d], xn0, fmaf(w9[3 * d + 1], xn1, w9[3 * d + 2] * xn2));
        b[d] = f2bf(cp);
        b[3 + d] = f2bf(cn);
      }
      b[6] = 0; b[7] = 0;
      *(short8*)&Ssh[2 * U_BBF + t * 8] = b;
    }
  }

  // field: this wave does ALL 6 s-tiles (col means finished inline per s)
  short8 aF[6];
#pragma unroll
  for (int mt = 0; mt < 6; ++mt)
    aF[mt] = *(const short8*)&Ssh[2 * U_ABF + (mt * 16 + l16) * 8];

  v2f rp2[6][2];
#pragma unroll
  for (int mt = 0; mt < 6; ++mt) {
    rp2[mt][0] = (v2f){0.f, 0.f};
    rp2[mt][1] = (v2f){0.f, 0.f};
  }

  const int g = unit >> 4;
  const int u15 = unit & 15;
  short* eb = epre_s + (size_t)g * 3072;

#pragma unroll
  for (int s = 0; s < 6; ++s) {
    short8 bF = *(const short8*)&Ssh[2 * U_BBF + (s * 16 + l16) * 8];
    floatx4 accv[6];
#pragma unroll
    for (int mt = 0; mt < 6; ++mt)
      accv[mt] = __builtin_amdgcn_mfma_f32_16x16x32_bf16(
          aF[mt], bF, (floatx4){0.f, 0.f, 0.f, 0.f}, 0, 0, 0);
    v2f csl = (v2f){0.f, 0.f};
#pragma unroll
    for (int mt = 0; mt < 6; ++mt) {
      v2f lo = (v2f){accv[mt][0], accv[mt][1]};
      v2f hi = (v2f){accv[mt][2], accv[mt][3]};
      v2f tl = 0.1f * lo;
      v2f th = 0.1f * hi;
      v2f fl, fh;
      fl.x = fmaxf(lo.x, tl.x); fl.y = fmaxf(lo.y, tl.y);
      fh.x = fmaxf(hi.x, th.x); fh.y = fmaxf(hi.y, th.y);
      rp2[mt][0] += fl;
      rp2[mt][1] += fh;
      csl += fl + fh;
    }
    // col mean for col s*16+l16: sum the 4 quads, write from quad 0
    float c = csl.x + csl.y;
    c += __shfl_xor(c, 16, 64);
    c += __shfl_xor(c, 32, 64);
    if (quad == 0) {
      int kidx = 96 + s * 16 + l16;
      int kf = kidx >> 5, rem = kidx & 31, q = rem >> 3, j = rem & 7;
      eb[kf * 512 + (q * 16 + u15) * 8 + j] = f2bf(c * (1.f / FLn));
    }
  }

  // row means: 16-lane (l16) butterfly per mt, 4 rows per quad
#pragma unroll
  for (int mt = 0; mt < 6; ++mt) {
    float r0 = rp2[mt][0].x, r1 = rp2[mt][0].y;
    float r2 = rp2[mt][1].x, r3 = rp2[mt][1].y;
#pragma unroll
    for (int off = 1; off < 16; off <<= 1) {
      r0 += __shfl_xor(r0, off, 64);
      r1 += __shfl_xor(r1, off, 64);
      r2 += __shfl_xor(r2, off, 64);
      r3 += __shfl_xor(r3, off, 64);
    }
    if (l16 == 0) {
      float vr[4] = {r0, r1, r2, r3};
#pragma unroll
      for (int r = 0; r < 4; ++r) {
        int i = mt * 16 + quad * 4 + r;
        int kf = i >> 5, rem = i & 31, q = rem >> 3, j = rem & 7;
        eb[kf * 512 + (q * 16 + u15) * 8 + j] = f2bf(vr[r] * (1.f / FLn));
      }
    }
  }
}

// ---------------- K6: fused tail, fragment-contiguous loads (R9 proven) -----
__global__ __launch_bounds__(512) void k6_fused_tail(
    const short* __restrict__ epre_s, const short* __restrict__ wB2s,
    const short* __restrict__ wB3s, const float* __restrict__ x,
    const float* __restrict__ rsb, const float* __restrict__ rsg,
    const float* __restrict__ rsbe, const float* __restrict__ rsm,
    const float* __restrict__ rsv,
    const float* __restrict__ clb1, const float* __restrict__ clg,
    const float* __restrict__ clbe, const float* __restrict__ clm,
    const float* __restrict__ clv,
    const float* __restrict__ clW2, const float* __restrict__ clb2,
    float* __restrict__ out) {
  __shared__ short ceT[16 * 584]; // 18.7 KB
  __shared__ float scr[8 * 32];
  const int tid = threadIdx.x;
  const int w = tid >> 6;
  const int lane = tid & 63;
  const int quad = lane >> 4;
  const int l16 = lane & 15;
  const int s0 = blockIdx.x * 16;

  // ---- phase A ----
  const int mt = w & 1;
  const int ng = w >> 1;  // 0..3
  short8 aF[6];
  {
    const short* arow = epre_s + (size_t)(blockIdx.x * 2 + mt) * 6 * 512 + lane * 8;
#pragma unroll
    for (int kf = 0; kf < 6; ++kf) aF[kf] = *(const short8*)(arow + kf * 512);
  }

  for (int nf = ng; nf < 18; nf += 4) {
    const short* brow = wB2s + (size_t)nf * 6 * 512 + lane * 8;
    floatx4 acc = (floatx4){0.f, 0.f, 0.f, 0.f};
#pragma unroll
    for (int kf = 0; kf < 6; ++kf) {
      short8 bF = *(const short8*)(brow + kf * 512);
      acc = __builtin_amdgcn_mfma_f32_16x16x32_bf16(aF[kf], bF, acc, 0, 0, 0);
    }
    const int n = nf * 16 + l16;
    const float sc = rsg[n] * rsqrtf(rsv[n] + EPS_BN);
    const float vb = rsb[n], mu = rsm[n], vbe = rsbe[n];
#pragma unroll
    for (int r = 0; r < 4; ++r) {
      int um = mt * 16 + quad * 4 + r;   // unit-in-block 0..31
      int trow = um >> 1;                // sample 0..15
      int cc = (um & 1) * 288 + n;       // col 0..575
      float y = acc[r] + vb;
      float o = (y - mu) * sc + vbe;
      float e = lrelu(o) + x[(size_t)(s0 + trow) * 576 + cc];
      ceT[trow * 584 + cc] = f2bf(e);
    }
  }
  __syncthreads();

  // ---- phase B (+ cl2 fold) ----
  float p0[4], p1[4];
#pragma unroll
  for (int r = 0; r < 4; ++r) { p0[r] = 0.f; p1[r] = 0.f; }

  for (int nt = w; nt < 18; nt += 8) {
    const short* brow = wB3s + (size_t)nt * 18 * 512 + lane * 8;
    floatx4 acc = (floatx4){0.f, 0.f, 0.f, 0.f};
#pragma unroll
    for (int kf = 0; kf < 18; ++kf) {
      short8 cF = *(const short8*)&ceT[l16 * 584 + kf * 32 + quad * 8];
      short8 bF = *(const short8*)(brow + kf * 512);
      acc = __builtin_amdgcn_mfma_f32_16x16x32_bf16(cF, bF, acc, 0, 0, 0);
    }
    const int n = nt * 16 + l16;
    const float sc = clg[n] * rsqrtf(clv[n] + EPS_BN);
    const float vb = clb1[n], mu = clm[n], vbe = clbe[n];
    const float w2a = clW2[n], w2b = clW2[288 + n];
#pragma unroll
    for (int r = 0; r < 4; ++r) {
      float y = acc[r] + vb;
      float hh = fmaxf((y - mu) * sc + vbe, 0.f);
      p0[r] = fmaf(hh, w2a, p0[r]);
      p1[r] = fmaf(hh, w2b, p1[r]);
    }
  }
#pragma unroll
  for (int r = 0; r < 4; ++r) {
#pragma unroll
    for (int off = 1; off < 16; off <<= 1) {
      p0[r] += __shfl_xor(p0[r], off, 64);
      p1[r] += __shfl_xor(p1[r], off, 64);
    }
  }
  if (l16 == 0) {
#pragma unroll
    for (int r = 0; r < 4; ++r) {
      scr[w * 32 + (quad * 4 + r) * 2 + 0] = p0[r];
      scr[w * 32 + (quad * 4 + r) * 2 + 1] = p1[r];
    }
  }
  __syncthreads();
  if (tid < 32) {
    int row = tid >> 1, o = tid & 1;
    float s = 0.f;
#pragma unroll
    for (int g = 0; g < 8; ++g) s += scr[g * 32 + row * 2 + o];
    out[(size_t)(s0 + row) * 2 + o] = s + clb2[o];
  }
}

extern "C" void kernel_launch(void* const* d_in, const int* in_sizes, int n_in,
                              void* d_out, int out_size, void* d_ws, size_t ws_size,
                              hipStream_t stream) {
  const float* x   = (const float*)d_in[0];
  const float* cw1 = (const float*)d_in[1];  const float* cb1 = (const float*)d_in[2];
  const float* cw2 = (const float*)d_in[3];  const float* cb2 = (const float*)d_in[4];
  const float* cw3 = (const float*)d_in[5];  const float* cb3 = (const float*)d_in[6];
  const float* cw4 = (const float*)d_in[7];  const float* cb4 = (const float*)d_in[8];
  const float* cw5 = (const float*)d_in[9];  const float* cb5 = (const float*)d_in[10];
  const float* cw6 = (const float*)d_in[11]; const float* cb6 = (const float*)d_in[12];
  const float* deW = (const float*)d_in[13]; const float* deb = (const float*)d_in[14];
  const float* rsW = (const float*)d_in[15]; const float* rsb = (const float*)d_in[16];
  const float* rsg = (const float*)d_in[17]; const float* rsbe = (const float*)d_in[18];
  const float* rsm = (const float*)d_in[19]; const float* rsv = (const float*)d_in[20];
  const float* clW1 = (const float*)d_in[21]; const float* clb1 = (const float*)d_in[22];
  const float* clg = (const float*)d_in[23]; const float* clbe = (const float*)d_in[24];
  const float* clm = (const float*)d_in[25]; const float* clv = (const float*)d_in[26];
  const float* clW2 = (const float*)d_in[27]; const float* clb2 = (const float*)d_in[28];

  short* ws     = (short*)d_ws;
  short* epre_s = ws;                         // 16384*192 bf16 (fragment order)
  short* wB2s   = ws + 16384 * 192;           // 18*6*512 bf16
  short* wB3s   = wB2s + 18 * 6 * 512;        // 18*18*512 bf16

  hipLaunchKernelGGL(k1_persample, dim3(4096), dim3(256), 0, stream, x,
                     cw1, cb1, cw2, cb2, cw3, cb3, cw4, cb4, cw5, cb5, cw6, cb6,
                     deW, deb, rsW, clW1, wB2s, wB3s, epre_s);
  hipLaunchKernelGGL(k6_fused_tail, dim3(512), dim3(512), 0, stream,
                     epre_s, wB2s, wB3s, x,
                     rsb, rsg, rsbe, rsm, rsv,
                     clb1, clg, clbe, clm, clv,
                     clW2, clb2, (float*)d_out);
}